// Round 6
// baseline (165.487 us; speedup 1.0000x reference)
//
#include <hip/hip_runtime.h>

#define BATCH 16
#define NN    256
#define E     128
#define NR    (BATCH*NN)
#define ZCAP  8
#define MAGIC 0x7F3A2B1C

typedef float f4 __attribute__((ext_vector_type(4)));

__device__ __forceinline__ float rlane(float v, int l) {
    return __uint_as_float((unsigned)__builtin_amdgcn_readlane((int)__float_as_uint(v), l));
}

// =====================================================================
// Single kernel. 256 blocks x 1024 threads (one block/CU, 16 waves).
// Theme of this version: broadcasts OFF the LDS pipe.
//  - s3: wave-uniform s_load_dwordx4 directly from Ws (SMEM pipe).
//  - s13/theta7/recurrence matvecs: A-operand distributed in lanes,
//    broadcast via v_readlane -> SGPR (VALU), LDS only for the one
//    cross-wave half-exchange (per-lane b32).
// Phase 2 runs redundantly in every block (r3 scheme).
// VGPR must stay <=64 (1024-thr block => 4 waves/SIMD cap).
// =====================================================================
__global__ __launch_bounds__(1024) void k_all(
    const float* __restrict__ xv,  const float* __restrict__ Ws,
    const float* __restrict__ t1w, const float* __restrict__ t1b,
    const float* __restrict__ t2w, const float* __restrict__ t2b,
    const float* __restrict__ t3w, const float* __restrict__ t3b,
    const float* __restrict__ t4w, const float* __restrict__ t4b,
    const float* __restrict__ t5w, const float* __restrict__ t5b,
    const float* __restrict__ t6w, const float* __restrict__ t6b,
    const float* __restrict__ t7w, const float* __restrict__ t7b,
    const float* __restrict__ lw,  const float* __restrict__ lb,
    float* __restrict__ s13g, float* __restrict__ zmu4g,
    float* __restrict__ s2b3g, float* __restrict__ gsumG,
    int* __restrict__ zcnt, int* __restrict__ doneA, int* __restrict__ flagA,
    float* __restrict__ out)
{
    (void)zmu4g; (void)s2b3g; (void)gsumG; (void)flagA;

    const int blk = blockIdx.x;
    const int b   = blk >> 4;
    const int bt  = blk & 15;
    const int j0  = bt * 16;
    const int r0  = b*NN + j0;
    const int t   = threadIdx.x;
    const int e   = t & 127;
    const int q   = t >> 7;                // 0..7
    const int p   = (t >> 6) & 1;          // wave parity within q-group
    const size_t bb = (size_t)b*NN*E;

    __shared__ __align__(16) float s3p[2][16][E]; // s3 partials; [0] = final
    __shared__ __align__(16) float hsl[16][E];    // hs rows; reused as mu4
    __shared__ __align__(16) float s13l[16][E];
    __shared__ __align__(16) float sQA[8][E];     // colsum partials
    __shared__ __align__(16) float csL[E];
    __shared__ __align__(16) float dbuf[E], s2bL[E];   // nz>0 path only
    __shared__ float zmuP[ZCAP][E], zmuN[ZCAP][E];
    __shared__ int   zmap[NN];
    __shared__ int   zlist[ZCAP];
    __shared__ int   nzs;
    __shared__ int   lcnt[16];
    __shared__ float sredO[16][2];
    __shared__ float sg2[2];

    const float* wb = Ws + (size_t)b*NN*NN;

    // ================= phase 1 =================
    float h0r, h1r;
    {   // hs: thread (e,q) -> rows 2q, 2q+1 (kept in regs + LDS)
        float b1 = t1b[e];
        float w0=t1w[e],w1=t1w[E+e],w2=t1w[2*E+e],w3=t1w[3*E+e],w4=t1w[4*E+e];
        const float* x0 = xv + (size_t)(r0 + q*2)*5;
        const float* x1 = xv + (size_t)(r0 + q*2 + 1)*5;
        h0r = fmaxf(b1 + x0[0]*w0+x0[1]*w1+x0[2]*w2+x0[3]*w3+x0[4]*w4, 0.f);
        h1r = fmaxf(b1 + x1[0]*w0+x1[1]*w1+x1[2]*w2+x1[3]*w3+x1[4]*w4, 0.f);
        hsl[q*2][e]   = h0r;
        hsl[q*2+1][e] = h1r;
    }
    {   // s3 partials via wave-uniform loads: wave (cq=q&3, ih=q>>2)
        // owns cols cq*4..+4, i-half ih; per-lane (a,c)=t4 at e.
        const int cq = q & 3, ih = q >> 2;
        const float a = t4w[e], c = t4b[e];
        const float* wcol = wb + (size_t)(ih*128)*NN + j0 + cq*4;
        float x0=0.f, x1=0.f, x2=0.f, x3=0.f;
        #pragma unroll 8
        for (int i = 0; i < 128; ++i) {
            f4 w = *(const f4*)(wcol + (size_t)i*NN);   // uniform -> s_load
            x0 += fmaxf(w.x*a + c, 0.f);
            x1 += fmaxf(w.y*a + c, 0.f);
            x2 += fmaxf(w.z*a + c, 0.f);
            x3 += fmaxf(w.w*a + c, 0.f);
        }
        s3p[ih][cq*4+0][e] = x0;
        s3p[ih][cq*4+1][e] = x1;
        s3p[ih][cq*4+2][e] = x2;
        s3p[ih][cq*4+3][e] = x3;
    }
    {   // conn-zero scan: wave w -> row j0+w; register shuffle-reduce
        const int w = t >> 6, l = t & 63;
        f4 v = *(const f4*)(wb + (size_t)(j0 + w)*NN + l*4);
        int c = (v.x<=0.f) + (v.y<=0.f) + (v.z<=0.f) + (v.w<=0.f);
        #pragma unroll
        for (int off = 32; off; off >>= 1) c += __shfl_down(c, off, 64);
        if (l == 0) lcnt[w] = c;
    }
    __syncthreads();                                   // B_a
    float s30, s31;
    {   // combine s3 halves: thread (e,q) owns rows 2q,2q+1 at col e
        const int jp = 2*q;
        s30 = s3p[0][jp][e]   + s3p[1][jp][e];
        s31 = s3p[0][jp+1][e] + s3p[1][jp+1][e];
        s3p[0][jp][e]   = s30;
        s3p[0][jp+1][e] = s31;
    }
    __syncthreads();                                   // B_c
    {   // s13 matvec via readlane: rows jp=2q, 2q+1
        const int jp = 2*q, eo = e ^ 64;
        float hO0 = hsl[jp][eo],    hO1 = hsl[jp+1][eo];
        float sO0 = s3p[0][jp][eo], sO1 = s3p[0][jp+1][eo];
        // lo-set holds elements k=0..63, hi-set k=64..127 (lane = k&63)
        float hL0 = p ? hO0 : h0r,  hH0 = p ? h0r : hO0;
        float hL1 = p ? hO1 : h1r,  hH1 = p ? h1r : hO1;
        float sL0 = p ? sO0 : s30,  sH0 = p ? s30 : sO0;
        float sL1 = p ? sO1 : s31,  sH1 = p ? s31 : sO1;
        float a0A=0.f, a1A=0.f, a0B=0.f, a1B=0.f;
        #pragma unroll 4
        for (int k = 0; k < 64; ++k) {
            float wl = lw[k*E + e], w3 = t3w[k*E + e];
            a0A += rlane(hL0,k)*wl + rlane(sL0,k)*w3;
            a1A += rlane(hL1,k)*wl + rlane(sL1,k)*w3;
        }
        #pragma unroll 4
        for (int k = 0; k < 64; ++k) {
            float wl = lw[(k+64)*E + e], w3 = t3w[(k+64)*E + e];
            a0B += rlane(hH0,k)*wl + rlane(sH0,k)*w3;
            a1B += rlane(hH1,k)*wl + rlane(sH1,k)*w3;
        }
        float bb2 = lb[e] + t3b[e];
        float v0 = a0A + a0B + bb2, v1 = a1A + a1B + bb2;
        s13l[jp][e] = v0;  s13l[jp+1][e] = v1;
        __hip_atomic_store(&s13g[(size_t)(r0+jp)*E + e],   v0,
                           __ATOMIC_RELAXED, __HIP_MEMORY_SCOPE_AGENT);
        __hip_atomic_store(&s13g[(size_t)(r0+jp+1)*E + e], v1,
                           __ATOMIC_RELAXED, __HIP_MEMORY_SCOPE_AGENT);
    }
    if (t < 16)
        __hip_atomic_store(&zcnt[r0 + t], lcnt[t],
                           __ATOMIC_RELAXED, __HIP_MEMORY_SCOPE_AGENT);
    __syncthreads();    // drains all agent stores (vmcnt before barrier)
    if (t == 0)
        __hip_atomic_store(&doneA[b*16 + bt], MAGIC,
                           __ATOMIC_RELEASE, __HIP_MEMORY_SCOPE_AGENT);

    // ============ phase 2: redundant recurrence in EVERY block ============
    if (t == 0) {
        int ok = 0, spins = 0;
        while (ok < 16 && spins < (1 << 18)) {
            ok = 0;
            #pragma unroll
            for (int i = 0; i < 16; ++i)
                ok += (__hip_atomic_load(&doneA[b*16+i], __ATOMIC_RELAXED,
                                         __HIP_MEMORY_SCOPE_AGENT) == MAGIC);
            if (ok < 16) __builtin_amdgcn_s_sleep(2);
            ++spins;
        }
        (void)__hip_atomic_load(&doneA[b*16], __ATOMIC_ACQUIRE,
                                __HIP_MEMORY_SCOPE_AGENT);
        nzs = 0;
    }
    if (t < NN) zmap[t] = -1;
    __syncthreads();
    if (t < NN) {
        if (__hip_atomic_load(&zcnt[b*NN + t], __ATOMIC_RELAXED,
                              __HIP_MEMORY_SCOPE_AGENT) > 0) {
            int s = atomicAdd(&nzs, 1);
            if (s < ZCAP) { zlist[s] = t; zmap[t] = s; }
        }
    }
    __syncthreads();
    const int nz = nzs < ZCAP ? nzs : ZCAP;

    // whole-batch s13 in registers: thread (e,q) -> rows q*32..+32
    float reg[32];
    #pragma unroll
    for (int j = 0; j < 32; ++j)
        reg[j] = __hip_atomic_load(&s13g[bb + (size_t)(q*32+j)*E + e],
                                   __ATOMIC_RELAXED, __HIP_MEMORY_SCOPE_AGENT);

    float s2b_r  = t2b[e];       // s2 for current it, in registers (per-e)
    float s2bP_r = s2b_r;
    float g_e = 0.f;             // gsum result (it==3)

    for (int it = 0; it < 4; ++it) {
        // -------- zero-row machinery (nz==0 on this dataset) --------
        if (nz > 0) {
            if (q == 0) s2bL[e] = s2b_r;
            __syncthreads();
            for (int z = 0; z < nz; ++z) {
                int j = zlist[z];
                float cp = 0.f;
                const float* wr = wb + (size_t)j*NN;
                if (it > 0) {
                    #pragma unroll
                    for (int u = 0; u < 32; ++u) {
                        int i = q*32 + u;
                        if (wr[i] <= 0.f) {
                            int zi = zmap[i];
                            cp += (zi >= 0) ? zmuP[zi][e]
                                            : fmaxf(reg[u] + s2bP_r, 0.f);
                        }
                    }
                }
                sQA[q][e] = cp;
                __syncthreads();
                if (q == 0) {
                    float s = 0.f;
                    #pragma unroll
                    for (int qq = 0; qq < 8; ++qq) s += sQA[qq][e];
                    dbuf[e] = s;
                }
                __syncthreads();
                float cb = 0.f;
                #pragma unroll 2
                for (int k = 0; k < E; k += 4) {
                    f4 d = *(const f4*)&dbuf[k];
                    cb += d.x*t2w[(k+0)*E+e] + d.y*t2w[(k+1)*E+e]
                        + d.z*t2w[(k+2)*E+e] + d.w*t2w[(k+3)*E+e];
                }
                if (q == 0) {
                    float sj = __hip_atomic_load(&s13g[bb+(size_t)j*E+e],
                                  __ATOMIC_RELAXED, __HIP_MEMORY_SCOPE_AGENT);
                    zmuN[z][e] = fmaxf(sj + s2b_r - cb, 0.f);
                }
                __syncthreads();
            }
        }

        // -------- colsum partial over my 32 rows --------
        float csp = 0.f;
        #pragma unroll
        for (int u = 0; u < 32; ++u) csp += fmaxf(reg[u] + s2b_r, 0.f);
        sQA[q][e] = csp;
        __syncthreads();                                   // B1

        // -------- per-lane cross-q reduce (distinct addrs, no bcast) ----
        float cs = sQA[0][e];
        #pragma unroll
        for (int qq = 1; qq < 8; ++qq) cs += sQA[qq][e];
        if (nz > 0) {
            for (int z = 0; z < nz; ++z) {
                int j = zlist[z];
                float sj = __hip_atomic_load(&s13g[bb+(size_t)j*E+e],
                              __ATOMIC_RELAXED, __HIP_MEMORY_SCOPE_AGENT);
                cs += zmuN[z][e] - fmaxf(sj + s2b_r, 0.f);
            }
        }
        if (q == 0) csL[e] = cs;
        s2bP_r = s2b_r;
        if (nz > 0 && q == 0)
            for (int z = 0; z < nz; ++z) zmuP[z][e] = zmuN[z][e];
        __syncthreads();                                   // B2

        // -------- matvec via readlane: full k per thread --------
        // it<3: W=t2w (next s2b);  it==3: W=t6w (gsum)
        {
            float csO = csL[e ^ 64];
            float cL = p ? csO : cs,  cH = p ? cs : csO;
            const float* W = (it < 3) ? t2w : t6w;
            float aA = (it < 3) ? t2b[e] : t6b[e];
            float aB = 0.f;
            #pragma unroll 4
            for (int k = 0; k < 64; ++k)
                aA += rlane(cL,k) * W[k*E + e];
            #pragma unroll 4
            for (int k = 0; k < 64; ++k)
                aB += rlane(cH,k) * W[(k+64)*E + e];
            if (it < 3) s2b_r = aA + aB;
            else        g_e   = aA + aB;
        }
    }

    // ===== tail: q0 -> gsum scalar; all -> mu4 rows (regs + LDS) =====
    if (q == 0) {
        float v = fmaxf(g_e, 0.f) * t5w[e];
        #pragma unroll
        for (int off = 32; off; off >>= 1) v += __shfl_down(v, off, 64);
        if ((t & 63) == 0) sg2[t >> 6] = v;
    }
    float m0r, m1r;
    {   // mu4 rows 2q,2q+1 -> regs + hsl (reuse as mul)
        const int jp = 2*q;
        int zi0 = zmap[j0 + jp], zi1 = zmap[j0 + jp + 1];
        m0r = (zi0 >= 0) ? zmuP[zi0][e] : fmaxf(s13l[jp][e]   + s2b_r, 0.f);
        m1r = (zi1 >= 0) ? zmuP[zi1][e] : fmaxf(s13l[jp+1][e] + s2b_r, 0.f);
        hsl[jp][e]   = m0r;
        hsl[jp+1][e] = m1r;
    }
    __syncthreads();

    {   // theta7 matvec via readlane + t5 right half + row reduction
        const int jp = 2*q, eo = e ^ 64;
        float mO0 = hsl[jp][eo], mO1 = hsl[jp+1][eo];
        float mL0 = p ? mO0 : m0r,  mH0 = p ? m0r : mO0;
        float mL1 = p ? mO1 : m1r,  mH1 = p ? m1r : mO1;
        float a0A=0.f, a1A=0.f, a0B=0.f, a1B=0.f;
        #pragma unroll 4
        for (int k = 0; k < 64; ++k) {
            float w7 = t7w[k*E + e];
            a0A += rlane(mL0,k)*w7;
            a1A += rlane(mL1,k)*w7;
        }
        #pragma unroll 4
        for (int k = 0; k < 64; ++k) {
            float w7 = t7w[(k+64)*E + e];
            a0B += rlane(mH0,k)*w7;
            a1B += rlane(mH1,k)*w7;
        }
        float b7 = t7b[e], w5 = t5w[E+e];
        float v0 = fmaxf(a0A + a0B + b7, 0.f) * w5;
        float v1 = fmaxf(a1A + a1B + b7, 0.f) * w5;
        #pragma unroll
        for (int off = 32; off; off >>= 1) {
            v0 += __shfl_down(v0, off, 64);
            v1 += __shfl_down(v1, off, 64);
        }
        if ((t & 63) == 0) {
            sredO[jp][p]   = v0;
            sredO[jp+1][p] = v1;
        }
    }
    __syncthreads();
    if (t < 16)
        out[r0 + t] = sredO[t][0] + sredO[t][1] + sg2[0] + sg2[1] + t5b[0];
}

extern "C" void kernel_launch(void* const* d_in, const int* in_sizes, int n_in,
                              void* d_out, int out_size, void* d_ws, size_t ws_size,
                              hipStream_t stream) {
    const float* xv  = (const float*)d_in[0];
    const float* Ws  = (const float*)d_in[1];
    const float* t1w = (const float*)d_in[2];  const float* t1b = (const float*)d_in[3];
    const float* t2w = (const float*)d_in[4];  const float* t2b = (const float*)d_in[5];
    const float* t3w = (const float*)d_in[6];  const float* t3b = (const float*)d_in[7];
    const float* t4w = (const float*)d_in[8];  const float* t4b = (const float*)d_in[9];
    const float* t5w = (const float*)d_in[10]; const float* t5b = (const float*)d_in[11];
    const float* t6w = (const float*)d_in[12]; const float* t6b = (const float*)d_in[13];
    const float* t7w = (const float*)d_in[14]; const float* t7b = (const float*)d_in[15];
    const float* lw  = (const float*)d_in[16]; const float* lb  = (const float*)d_in[17];
    float* outp = (float*)d_out;

    float* ws = (float*)d_ws;
    const int RE = NR*E;                    // 524288
    float* s13g  = ws;
    float* zmu4g = ws + RE;
    float* s2b3g = ws + 2*RE;               // BATCH*E
    float* gsumG = s2b3g + BATCH*E;         // 64
    int*   zcnt  = (int*)(gsumG + 64);      // NR
    int*   doneA = zcnt + NR + 64;          // BATCH*16
    int*   flagA = doneA + BATCH*16 + 64;   // BATCH

    k_all<<<256, 1024, 0, stream>>>(xv, Ws, t1w, t1b, t2w, t2b, t3w, t3b,
                                    t4w, t4b, t5w, t5b, t6w, t6b, t7w, t7b,
                                    lw, lb, s13g, zmu4g, s2b3g, gsumG,
                                    zcnt, doneA, flagA, outp);
}

// Round 8
// 132.577 us; speedup vs baseline: 1.2482x; 1.2482x over previous
//
#include <hip/hip_runtime.h>

#define BATCH 16
#define NN    256
#define E     128
#define NR    (BATCH*NN)
#define ZCAP  8
#define KP    132          // [row][k] stride: 132 floats = 528 B, 16B-aligned

typedef float f4 __attribute__((ext_vector_type(4)));
typedef float f2 __attribute__((ext_vector_type(2)));

// =====================================================================
// THREE kernels; dispatch boundaries replace the spin rendezvous.
//  k_p1 (256 x 1024): Ws col-tile -> LDS; s3 from LDS; hs; zero-scan;
//        s13 matvec -> s13g, zcnt (plain stores).
//  k_p2 (16 x 1024):  recurrence per batch (r3/r5-proven body);
//        publishes s2b3g, gsumG, zmu4g.
//  k_p3 (256 x 1024): mu4 = relu(s13+s2b); theta7 + theta5 -> out.
// Phase bodies verbatim from the 49us r5 kernel. Purpose of this round:
// per-phase rocprof attribution + removal of spin/redundancy machinery.
// (Resubmitted unchanged: round-7 failure was a container/broker error,
//  not a kernel verdict.)
// =====================================================================

__global__ __launch_bounds__(1024) void k_p1(
    const float* __restrict__ xv,  const float* __restrict__ Ws,
    const float* __restrict__ t1w, const float* __restrict__ t1b,
    const float* __restrict__ t3w, const float* __restrict__ t3b,
    const float* __restrict__ t4w, const float* __restrict__ t4b,
    const float* __restrict__ lw,  const float* __restrict__ lb,
    float* __restrict__ s13g, int* __restrict__ zcnt)
{
    const int blk = blockIdx.x;
    const int b   = blk >> 4;
    const int bt  = blk & 15;
    const int j0  = bt * 16;
    const int r0  = b*NN + j0;
    const int t   = threadIdx.x;
    const int e   = t & 127;
    const int q   = t >> 7;                // 0..7

    __shared__ __align__(16) float wst[NN][16];   // Ws[:, j0:j0+16] tile
    __shared__ __align__(16) float s3l[16][KP];   // s3 [col j][emb k]
    __shared__ __align__(16) float hsl[16][KP];   // hs [row][emb k]
    __shared__ int lcnt[16];

    const float* wb = Ws + (size_t)b*NN*NN;

    {   // stage Ws column-tile: thread -> (i = t>>2, jq = (t&3)*4), f4
        const int i = t >> 2, jq = (t & 3) * 4;
        *(f4*)&wst[i][jq] = *(const f4*)(wb + (size_t)i*NN + j0 + jq);
    }
    {   // hs: thread (e,q) -> rows q*2, q*2+1; layout [row][k]
        float b1 = t1b[e];
        float w0=t1w[e],w1=t1w[E+e],w2=t1w[2*E+e],w3=t1w[3*E+e],w4=t1w[4*E+e];
        #pragma unroll
        for (int rr = 0; rr < 2; ++rr) {
            const float* x = xv + (size_t)(r0 + q*2 + rr)*5;
            hsl[q*2+rr][e] =
                fmaxf(b1 + x[0]*w0+x[1]*w1+x[2]*w2+x[3]*w3+x[4]*w4, 0.f);
        }
    }
    {   // conn-zero scan: wave w -> row j0+w; register shuffle-reduce
        const int w = t >> 6, l = t & 63;
        f4 v = *(const f4*)(wb + (size_t)(j0 + w)*NN + l*4);
        int c = (v.x<=0.f) + (v.y<=0.f) + (v.z<=0.f) + (v.w<=0.f);
        #pragma unroll
        for (int off = 32; off; off >>= 1) c += __shfl_down(c, off, 64);
        if (l == 0) lcnt[w] = c;
    }
    __syncthreads();                 // wst staged, hsl written, lcnt written
    {   // s3 from LDS: thread (e,q) owns cols jp=2q, 2q+1; emb e
        const int jp = 2*q;
        const float a = t4w[e], c = t4b[e];
        float x0 = 0.f, x1 = 0.f;
        const f2* wp = (const f2*)&wst[0][jp];   // stride 16 floats = 8 f2
        #pragma unroll 8
        for (int i = 0; i < NN; ++i) {
            f2 w = wp[i*8];
            x0 += fmaxf(w.x*a + c, 0.f);
            x1 += fmaxf(w.y*a + c, 0.f);
        }
        s3l[jp][e]   = x0;
        s3l[jp+1][e] = x1;
    }
    __syncthreads();
    {   // s13 matvec: thread (e,q) -> rows jp=q*2, jp+1; b128 LDS over k
        const int jp = q*2;
        float acc0 = 0.f, acc1 = 0.f;
        #pragma unroll 2
        for (int k0 = 0; k0 < E; k0 += 4) {
            f4 h0 = *(const f4*)&hsl[jp][k0];
            f4 h1 = *(const f4*)&hsl[jp+1][k0];
            f4 s0 = *(const f4*)&s3l[jp][k0];
            f4 s1 = *(const f4*)&s3l[jp+1][k0];
            #pragma unroll
            for (int m = 0; m < 4; ++m) {
                float wl = lw[(k0+m)*E + e], w3 = t3w[(k0+m)*E + e];
                acc0 += h0[m]*wl + s0[m]*w3;
                acc1 += h1[m]*wl + s1[m]*w3;
            }
        }
        float bb2 = lb[e] + t3b[e];
        s13g[(size_t)(r0+jp)*E + e]   = acc0 + bb2;
        s13g[(size_t)(r0+jp+1)*E + e] = acc1 + bb2;
    }
    if (t < 16) zcnt[r0 + t] = lcnt[t];
}

__global__ __launch_bounds__(1024) void k_p2(
    const float* __restrict__ Ws,
    const float* __restrict__ t2w, const float* __restrict__ t2b,
    const float* __restrict__ t5w,
    const float* __restrict__ t6w, const float* __restrict__ t6b,
    const float* __restrict__ s13g, const int* __restrict__ zcnt,
    float* __restrict__ s2b3g, float* __restrict__ gsumG,
    float* __restrict__ zmu4g)
{
    const int b = blockIdx.x;
    const int t = threadIdx.x;
    const int e = t & 127;
    const int q = t >> 7;                  // 0..7
    const size_t bb = (size_t)b*NN*E;

    __shared__ __align__(16) float sQA[8][E];     // colsum partials
    __shared__ __align__(16) float sQB[8][E];     // matvec partials
    __shared__ __align__(16) float dbuf[E], s2bL[E];
    __shared__ float zmuP[ZCAP][E], zmuN[ZCAP][E];
    __shared__ int   zmap[NN];
    __shared__ int   zlist[ZCAP];
    __shared__ int   nzs;
    __shared__ float sg2[2];

    const float* wb = Ws + (size_t)b*NN*NN;

    if (t == 0) nzs = 0;
    if (t < NN) zmap[t] = -1;
    __syncthreads();
    if (t < NN) {
        if (zcnt[b*NN + t] > 0) {
            int s = atomicAdd(&nzs, 1);
            if (s < ZCAP) { zlist[s] = t; zmap[t] = s; }
        }
    }
    __syncthreads();
    const int nz = nzs < ZCAP ? nzs : ZCAP;

    // whole-batch s13 in registers: thread (e,q) -> rows q*32..+32
    float reg[32];
    #pragma unroll
    for (int j = 0; j < 32; ++j)
        reg[j] = s13g[bb + (size_t)(q*32+j)*E + e];

    float s2b_r  = t2b[e];       // s2(it+1) for current it, in registers
    float s2bP_r = s2b_r;

    for (int it = 0; it < 4; ++it) {
        // -------- zero-row machinery (nz==0 on this dataset) --------
        if (nz > 0) {
            if (q == 0) s2bL[e] = s2b_r;
            __syncthreads();
            for (int z = 0; z < nz; ++z) {
                int j = zlist[z];
                float cp = 0.f;
                const float* wr = wb + (size_t)j*NN;
                if (it > 0) {
                    #pragma unroll
                    for (int u = 0; u < 32; ++u) {
                        int i = q*32 + u;
                        if (wr[i] <= 0.f) {
                            int zi = zmap[i];
                            cp += (zi >= 0) ? zmuP[zi][e]
                                            : fmaxf(reg[u] + s2bP_r, 0.f);
                        }
                    }
                }
                sQA[q][e] = cp;
                __syncthreads();
                if (q == 0) {
                    float s = 0.f;
                    #pragma unroll
                    for (int qq = 0; qq < 8; ++qq) s += sQA[qq][e];
                    dbuf[e] = s;
                }
                __syncthreads();
                float cb = 0.f;
                #pragma unroll 2
                for (int k = 0; k < E; k += 4) {
                    f4 d = *(const f4*)&dbuf[k];
                    cb += d.x*t2w[(k+0)*E+e] + d.y*t2w[(k+1)*E+e]
                        + d.z*t2w[(k+2)*E+e] + d.w*t2w[(k+3)*E+e];
                }
                if (q == 0) {
                    float sj = s13g[bb+(size_t)j*E+e];
                    zmuN[z][e] = fmaxf(sj + s2b_r - cb, 0.f);
                }
                __syncthreads();
            }
        }

        // -------- colsum partial over my 32 rows --------
        float csp = 0.f;
        #pragma unroll
        for (int u = 0; u < 32; ++u) csp += fmaxf(reg[u] + s2b_r, 0.f);
        sQA[q][e] = csp;
        __syncthreads();                                   // B1

        // -------- consumer-redundant cs reduce + matvec partial --------
        // it<3: W=t2w (next s2b);  it==3: W=t6w (gsum)
        const float* W = (it < 3) ? t2w : t6w;
        float pa = 0.f;
        #pragma unroll
        for (int g4 = 0; g4 < 4; ++g4) {
            const int k0 = q*16 + g4*4;
            f4 c = *(const f4*)&sQA[0][k0];
            #pragma unroll
            for (int qq = 1; qq < 8; ++qq) {
                f4 d = *(const f4*)&sQA[qq][k0];
                c.x += d.x; c.y += d.y; c.z += d.z; c.w += d.w;
            }
            if (nz > 0) {
                for (int z = 0; z < nz; ++z) {
                    int j = zlist[z];
                    #pragma unroll
                    for (int m = 0; m < 4; ++m) {
                        float sj = s13g[bb+(size_t)j*E + k0 + m];
                        c[m] += zmuN[z][k0+m] - fmaxf(sj + s2bL[k0+m], 0.f);
                    }
                }
            }
            pa += c.x*W[(k0+0)*E+e] + c.y*W[(k0+1)*E+e]
                + c.z*W[(k0+2)*E+e] + c.w*W[(k0+3)*E+e];
        }
        sQB[q][e] = pa;
        s2bP_r = s2b_r;
        if (nz > 0 && q == 0)
            for (int z = 0; z < nz; ++z) zmuP[z][e] = zmuN[z][e];
        __syncthreads();                                   // B2

        if (it < 3) {
            float s = t2b[e];
            #pragma unroll
            for (int qq = 0; qq < 8; ++qq) s += sQB[qq][e];
            s2b_r = s;          // identical FP order in every thread
        }
    }

    // ===== tail: publish s2b, gsum, zero-row mu4 =====
    if (q == 0) {
        s2b3g[b*E + e] = s2b_r;
        float g = t6b[e];
        #pragma unroll
        for (int qq = 0; qq < 8; ++qq) g += sQB[qq][e];
        float v = fmaxf(g, 0.f) * t5w[e];
        #pragma unroll
        for (int off = 32; off; off >>= 1) v += __shfl_down(v, off, 64);
        if ((t & 63) == 0) sg2[t >> 6] = v;
        for (int z = 0; z < nz; ++z)
            zmu4g[bb + (size_t)zlist[z]*E + e] = zmuP[z][e];
    }
    if (q == 1 && nzs > ZCAP) {
        for (int j = 0; j < NN; ++j) {
            if (zcnt[b*NN + j] > 0 && zmap[j] < 0) {
                float sj = s13g[bb + (size_t)j*E + e];
                zmu4g[bb + (size_t)j*E + e] = fmaxf(sj + s2b_r, 0.f);
            }
        }
    }
    __syncthreads();
    if (t == 0) gsumG[b] = sg2[0] + sg2[1];
}

__global__ __launch_bounds__(1024) void k_p3(
    const float* __restrict__ t5w, const float* __restrict__ t5b,
    const float* __restrict__ t7w, const float* __restrict__ t7b,
    const float* __restrict__ s13g, const int* __restrict__ zcnt,
    const float* __restrict__ s2b3g, const float* __restrict__ gsumG,
    const float* __restrict__ zmu4g,
    float* __restrict__ out)
{
    const int blk = blockIdx.x;
    const int b   = blk >> 4;
    const int bt  = blk & 15;
    const int j0  = bt * 16;
    const int r0  = b*NN + j0;
    const int t   = threadIdx.x;
    const int e   = t & 127;
    const int q   = t >> 7;                // 0..7

    __shared__ __align__(16) float hsl[16][KP];   // mu4 [row][k]
    __shared__ float sredO[16][2];

    {   // mu4 rows jp=2q,2q+1
        const int jp = 2*q;
        float s2e = s2b3g[b*E + e];
        #pragma unroll
        for (int rr = 0; rr < 2; ++rr) {
            int row = jp + rr;
            float v;
            if (zcnt[r0 + row] > 0)
                v = zmu4g[(size_t)(r0+row)*E + e];
            else
                v = fmaxf(s13g[(size_t)(r0+row)*E + e] + s2e, 0.f);
            hsl[row][e] = v;
        }
    }
    __syncthreads();
    {   // theta7 matvec + t5 right half + row reduction; b128 LDS over k
        const int jp = 2*q;
        float a0 = 0.f, a1 = 0.f;
        #pragma unroll 2
        for (int k0 = 0; k0 < E; k0 += 4) {
            f4 m0 = *(const f4*)&hsl[jp][k0];
            f4 m1 = *(const f4*)&hsl[jp+1][k0];
            #pragma unroll
            for (int m = 0; m < 4; ++m) {
                float w7 = t7w[(k0+m)*E + e];
                a0 += m0[m]*w7;
                a1 += m1[m]*w7;
            }
        }
        float b7 = t7b[e], w5 = t5w[E+e];
        float v0 = fmaxf(a0 + b7, 0.f) * w5;
        float v1 = fmaxf(a1 + b7, 0.f) * w5;
        #pragma unroll
        for (int off = 32; off; off >>= 1) {
            v0 += __shfl_down(v0, off, 64);
            v1 += __shfl_down(v1, off, 64);
        }
        if ((t & 63) == 0) {
            sredO[jp][e >> 6]   = v0;
            sredO[jp+1][e >> 6] = v1;
        }
    }
    __syncthreads();
    if (t < 16)
        out[r0 + t] = sredO[t][0] + sredO[t][1] + gsumG[b] + t5b[0];
}

extern "C" void kernel_launch(void* const* d_in, const int* in_sizes, int n_in,
                              void* d_out, int out_size, void* d_ws, size_t ws_size,
                              hipStream_t stream) {
    const float* xv  = (const float*)d_in[0];
    const float* Ws  = (const float*)d_in[1];
    const float* t1w = (const float*)d_in[2];  const float* t1b = (const float*)d_in[3];
    const float* t2w = (const float*)d_in[4];  const float* t2b = (const float*)d_in[5];
    const float* t3w = (const float*)d_in[6];  const float* t3b = (const float*)d_in[7];
    const float* t4w = (const float*)d_in[8];  const float* t4b = (const float*)d_in[9];
    const float* t5w = (const float*)d_in[10]; const float* t5b = (const float*)d_in[11];
    const float* t6w = (const float*)d_in[12]; const float* t6b = (const float*)d_in[13];
    const float* t7w = (const float*)d_in[14]; const float* t7b = (const float*)d_in[15];
    const float* lw  = (const float*)d_in[16]; const float* lb  = (const float*)d_in[17];
    float* outp = (float*)d_out;

    float* ws = (float*)d_ws;
    const int RE = NR*E;                    // 524288
    float* s13g  = ws;
    float* zmu4g = ws + RE;
    float* s2b3g = ws + 2*RE;               // BATCH*E
    float* gsumG = s2b3g + BATCH*E;         // BATCH
    int*   zcnt  = (int*)(gsumG + 64);      // NR

    k_p1<<<256, 1024, 0, stream>>>(xv, Ws, t1w, t1b, t3w, t3b, t4w, t4b,
                                   lw, lb, s13g, zcnt);
    k_p2<<<BATCH, 1024, 0, stream>>>(Ws, t2w, t2b, t5w, t6w, t6b,
                                     s13g, zcnt, s2b3g, gsumG, zmu4g);
    k_p3<<<256, 1024, 0, stream>>>(t5w, t5b, t7w, t7b, s13g, zcnt,
                                   s2b3g, gsumG, zmu4g, outp);
}